// Round 17
// baseline (620.629 us; speedup 1.0000x reference)
//
#include <hip/hip_runtime.h>
#include <hip/hip_bf16.h>

// VectorQuantizer B=32768, K=4096, D=512, fp32 in/out.
// Out concat (f32): quantized_st[B*512] | indices[B] | loss | perplexity | encodings[B*4096].
// R17: int8 MFMA screen with ZERO LDS and ZERO barriers. A (32 rows x full K i8)
// resident in 64 VGPRs/wave; B streams from L2-resident Ei8 (2MB) as coalesced
// dwordx4; mfma_i32_32x32x32_i8 into 4 independent int accs (exact int merge).
// Screen score = -2*sx*se*dot (esq term <= 3e-5 << margin, dropped); MARG 1.2e-3.
// numpy-fp32 rescore (verbatim R5-R16) still decides the argmin exactly.

typedef __attribute__((ext_vector_type(4)))  int i32x4;
typedef __attribute__((ext_vector_type(16))) int i32x16;

#define BB 32768
#define KK 4096
#define DD 512

#define IDX_OFF  (BB*DD)
#define LOSS_OFF (IDX_OFF + BB)
#define PERP_OFF (LOSS_OFF + 1)
#define ENC_OFF  (PERP_OFF + 1)

// ws byte offsets
#define WSB_XSQ  0
#define WSB_ESQ  131072
#define WSB_IDX  147456
#define WSB_HIST 278528
#define WSB_LOSS 294912
#define WSB_EI8  294928          // 2 MB: E int8, frag-packed [(tile*16+kt)*64+lane]*16B
#define WSB_XI8  4489232         // 16 MB: X int8, frag-packed [(rowblk*16+kt)*64+lane]*16B
#define WSB_PART 38043664        // 8 MB: uint2 partials [32][32768]

#define MARG 1.2e-3f
#define NCAND 16
// score scale: 2 * (6/127) * (1/(4096*127)) = 12/66064384
#define NEG2SXSE (-1.816387e-7f)

static __device__ __forceinline__ unsigned int packscore(float s, int col) {
    unsigned int u = __float_as_uint(s);
    u ^= (u & 0x80000000u) ? 0xFFFFFFFFu : 0x80000000u;
    return (u & 0xFFFFF000u) | (unsigned int)col;
}
static __device__ __forceinline__ float unpackscore(unsigned int p) {
    unsigned int u = p & 0xFFFFF000u;
    u = (u & 0x80000000u) ? (u ^ 0x80000000u) : ~u;
    return __uint_as_float(u);
}

static __device__ __forceinline__ int q8x(float x) {   // clamp +-6, scale 127/6
    return __float2int_rn(fminf(6.f, fmaxf(-6.f, x)) * (127.f / 6.f));
}
static __device__ __forceinline__ int q8e(float e) {   // scale 127*4096
    float v = e * 520192.0f;
    return __float2int_rn(fminf(127.f, fmaxf(-127.f, v)));
}

// numpy-emulated row sum-of-squares (pairwise-128 + AVX512 lane fold; tree
// bit-identical R5-R16) fused with X int8 fragment-packing.
__global__ __launch_bounds__(256) void npsum_pack_kernel(const float* __restrict__ X,
                                                         const float* __restrict__ E,
                                                         float* __restrict__ xsq,
                                                         float* __restrict__ esq,
                                                         char* __restrict__ Xi8) {
    __shared__ float sq[4][512];
    __shared__ float ub[4][64];
    __shared__ float bb[4][4];
    int w = threadIdx.x >> 6, lane = threadIdx.x & 63;
    int row = blockIdx.x * 4 + w;
    const float* src; float* dst;
    bool isx = (row < BB);
    if (isx) { src = X + (size_t)row * DD;        dst = xsq + row; }
    else     { src = E + (size_t)(row - BB) * DD; dst = esq + (row - BB); }
    const float4* s4 = (const float4*)(src + lane * 8);
    float4 a = s4[0], b = s4[1];
    sq[w][lane * 8 + 0] = __fmul_rn(a.x, a.x);
    sq[w][lane * 8 + 1] = __fmul_rn(a.y, a.y);
    sq[w][lane * 8 + 2] = __fmul_rn(a.z, a.z);
    sq[w][lane * 8 + 3] = __fmul_rn(a.w, a.w);
    sq[w][lane * 8 + 4] = __fmul_rn(b.x, b.x);
    sq[w][lane * 8 + 5] = __fmul_rn(b.y, b.y);
    sq[w][lane * 8 + 6] = __fmul_rn(b.z, b.z);
    sq[w][lane * 8 + 7] = __fmul_rn(b.w, b.w);
    if (isx) {   // Xi8 frag-pack: k = lane*8..+7 -> kt=lane>>2, g=(lane&3)>>1, jhalf=lane&1
        int v0 = q8x(a.x), v1 = q8x(a.y), v2 = q8x(a.z), v3 = q8x(a.w);
        int v4 = q8x(b.x), v5 = q8x(b.y), v6 = q8x(b.z), v7 = q8x(b.w);
        unsigned int lo = (v0 & 255) | ((v1 & 255) << 8) | ((v2 & 255) << 16) | ((v3 & 255) << 24);
        unsigned int hi = (v4 & 255) | ((v5 & 255) << 8) | ((v6 & 255) << 16) | ((v7 & 255) << 24);
        int kt = lane >> 2, g = (lane & 3) >> 1;
        size_t unit = ((size_t)((row >> 5) * 16 + kt)) * 64
                    + (size_t)(g * 32 + (row & 31));
        *(uint2*)(Xi8 + unit * 16 + (lane & 1) * 8) = make_uint2(lo, hi);
    }
    __syncthreads();
    {
        int b2 = lane >> 4, l = lane & 15;
        const float* s = &sq[w][b2 * 128];
        float t = __fadd_rn(
            __fadd_rn(__fadd_rn(s[l], s[16 + l]), __fadd_rn(s[32 + l], s[48 + l])),
            __fadd_rn(__fadd_rn(s[64 + l], s[80 + l]), __fadd_rn(s[96 + l], s[112 + l])));
        ub[w][lane] = t;
    }
    __syncthreads();
    if (lane < 4) {
        const float* u = &ub[w][lane * 16];
        float T3[8], T6[4];
        #pragma unroll
        for (int i = 0; i < 8; ++i) T3[i] = __fadd_rn(u[i], u[i + 8]);
        #pragma unroll
        for (int i = 0; i < 4; ++i) T6[i] = __fadd_rn(T3[i], T3[i + 4]);
        bb[w][lane] = __fadd_rn(__fadd_rn(T6[0], T6[2]), __fadd_rn(T6[1], T6[3]));
    }
    __syncthreads();
    if (lane == 0)
        *dst = __fadd_rn(__fadd_rn(bb[w][0], bb[w][1]), __fadd_rn(bb[w][2], bb[w][3]));
}

// E fp32 -> int8 frag-packed. Thread = one 16B unit (tile T, kt, lane):
// col = T*32 + (lane&31), k = kt*32 + (lane>>5)*16 + j, j=0..15. Fused init.
__global__ __launch_bounds__(256) void packEi8_kernel(const float* __restrict__ E,
                                                      char* __restrict__ Ei8,
                                                      int* __restrict__ hist,
                                                      double* __restrict__ loss_acc) {
    int t = blockIdx.x * 256 + threadIdx.x;     // 131072 units, grid 512
    if (t < KK) hist[t] = 0;
    if (t == KK) *loss_acc = 0.0;
    int lane = t & 63, rest = t >> 6;
    int kt = rest & 15, T = rest >> 4;
    int col = T * 32 + (lane & 31);
    int k0  = kt * 32 + (lane >> 5) * 16;
    const float4* s = (const float4*)(E + (size_t)col * DD + k0);
    unsigned int u[4];
    #pragma unroll
    for (int q = 0; q < 4; ++q) {
        float4 v = s[q];
        int b0 = q8e(v.x), b1 = q8e(v.y), b2 = q8e(v.z), b3 = q8e(v.w);
        u[q] = (b0 & 255) | ((b1 & 255) << 8) | ((b2 & 255) << 16) | ((b3 & 255) << 24);
    }
    *(uint4*)(Ei8 + (size_t)t * 16) = make_uint4(u[0], u[1], u[2], u[3]);
}

// i8 screen: grid 256 x 256thr = 1024 independent waves, 32 rows each.
// No LDS, no barriers. 128 B-tiles x {16 loads, 16 MFMA, int merge, top2}.
__global__ __launch_bounds__(256, 1) void iscreen(
    const char* __restrict__ Xi8, const char* __restrict__ Ei8,
    uint2* __restrict__ partials)
{
    const int tid = threadIdx.x;
    const int w = tid >> 6, lane = tid & 63;
    const int bid = blockIdx.x;
    const int orig = (bid & 7) * 32 + (bid >> 3);   // bijective: 256 % 8 == 0
    const int wid = orig * 4 + w;                   // 0..1023
    const int row0 = wid * 32;

    // A fragments: 32 rows x full K, 64 VGPR
    i32x4 af[16];
    {
        const i32x4* Ap = (const i32x4*)(Xi8 + (size_t)wid * 16384) + lane;
        #pragma unroll
        for (int kt = 0; kt < 16; ++kt) af[kt] = Ap[kt * 64];
    }

    unsigned int p1[16], p2[16];
    #pragma unroll
    for (int r = 0; r < 16; ++r) { p1[r] = 0xFFFFFFFFu; p2[r] = 0xFFFFFFFFu; }

    const i32x4* Bp = (const i32x4*)Ei8 + lane;
    const int cls = lane & 31;

    for (int t = 0; t < 128; ++t) {
        i32x4 bfr[16];
        #pragma unroll
        for (int kt = 0; kt < 16; ++kt) bfr[kt] = Bp[(t * 16 + kt) * 64];
        i32x16 a0, a1, a2, a3;
        #pragma unroll
        for (int i = 0; i < 16; ++i) { a0[i] = 0; a1[i] = 0; a2[i] = 0; a3[i] = 0; }
        #pragma unroll
        for (int q = 0; q < 4; ++q) {
            a0 = __builtin_amdgcn_mfma_i32_32x32x32_i8(af[q],      bfr[q],      a0, 0, 0, 0);
            a1 = __builtin_amdgcn_mfma_i32_32x32x32_i8(af[4 + q],  bfr[4 + q],  a1, 0, 0, 0);
            a2 = __builtin_amdgcn_mfma_i32_32x32x32_i8(af[8 + q],  bfr[8 + q],  a2, 0, 0, 0);
            a3 = __builtin_amdgcn_mfma_i32_32x32x32_i8(af[12 + q], bfr[12 + q], a3, 0, 0, 0);
        }
        const int colt = t * 32 + cls;
        #pragma unroll
        for (int r = 0; r < 16; ++r) {
            int ds = (a0[r] + a1[r]) + (a2[r] + a3[r]);   // exact int merge
            float sc = (float)ds * NEG2SXSE;              // esq dropped (<=3e-5 << MARG)
            unsigned int q = packscore(sc, colt);
            if (q < p1[r]) { p2[r] = p1[r]; p1[r] = q; }
            else if (q < p2[r]) p2[r] = q;
        }
    }

    // C layout (m74/m101): col=lane&31, row=(r&3)+8*(r>>2)+4*(lane>>5)
    #pragma unroll
    for (int r = 0; r < 16; ++r) {
        int rowl = (r & 3) + 8 * (r >> 2) + 4 * (lane >> 5);
        partials[(size_t)cls * BB + row0 + rowl] = make_uint2(p1[r], p2[r]);
    }
}

// merge 32 partials -> candidates -> numpy-fp32 rescore (verbatim R5-R16)
__global__ __launch_bounds__(256) void reduce_kernel(
    const float* __restrict__ X, const float* __restrict__ E,
    const float* __restrict__ xsqw, const float* __restrict__ esqw,
    const uint2* __restrict__ partials, int* __restrict__ idxbuf,
    int* __restrict__ hist, double* __restrict__ loss_acc,
    float* __restrict__ out)
{
    __shared__ double lred[256];
    const int row = blockIdx.x * 256 + threadIdx.x;
    unsigned int m = 0xFFFFFFFFu;
    for (int e = 0; e < 32; ++e) m = min(m, partials[(size_t)e * BB + row].x);
    float lim = unpackscore(m) + MARG;
    int cand[NCAND]; int nc = 0;
    for (int e = 0; e < 32; ++e) {
        uint2 p = partials[(size_t)e * BB + row];
        if (unpackscore(p.x) <= lim && nc < NCAND) cand[nc++] = (int)(p.x & 0xFFFu);
        if (unpackscore(p.y) <= lim && nc < NCAND) cand[nc++] = (int)(p.y & 0xFFFu);
    }
    const float* xr = X + (size_t)row * DD;
    float xs = xsqw[row];
    float bd = 3.0e38f; int bk = 0x7fffffff;
    for (int cidx = 0; cidx < nc; ++cidx) {
        int k = cand[cidx] & (KK - 1);
        const float* er = E + (size_t)k * DD;
        float q1 = 0.f, q2 = 0.f;
        for (int d = 0; d < 384; ++d)   q1 = fmaf(xr[d], er[d], q1);
        for (int d = 384; d < 512; ++d) q2 = fmaf(xr[d], er[d], q2);
        float dot = __fadd_rn(q1, q2);
        float t1  = __fadd_rn(xs, esqw[k]);
        float dnp = __fsub_rn(t1, __fmul_rn(2.0f, dot));
        if (dnp < bd || (dnp == bd && k < bk)) { bd = dnp; bk = k; }
    }
    const float* er = E + (size_t)bk * DD;
    double ls = 0.0;
    for (int d = 0; d < DD; ++d) {
        double df = (double)xr[d] - (double)er[d];
        ls = fma(df, df, ls);
    }
    idxbuf[row] = bk;
    out[IDX_OFF + row] = (float)bk;
    atomicAdd(&hist[bk], 1);
    lred[threadIdx.x] = ls;
    __syncthreads();
    for (int t = 128; t > 0; t >>= 1) {
        if (threadIdx.x < t) lred[threadIdx.x] += lred[threadIdx.x + t];
        __syncthreads();
    }
    if (threadIdx.x == 0) atomicAdd(loss_acc, lred[0]);
}

// one block per row: quantized gather (coalesced) + one-hot row
__global__ __launch_bounds__(256) void encq_kernel(const int* __restrict__ idxbuf,
                                                   const float* __restrict__ E,
                                                   float* __restrict__ out) {
    int row = blockIdx.x;
    int idx = idxbuf[row];
    ((float2*)out)[(size_t)row * 256 + threadIdx.x] =
        ((const float2*)E)[(size_t)idx * 256 + threadIdx.x];
    float2* erow = (float2*)(out + ENC_OFF) + (size_t)row * (KK / 2);
    int half = idx >> 1;
    float2 one;
    if (idx & 1) { one.x = 0.f; one.y = 1.f; } else { one.x = 1.f; one.y = 0.f; }
    float2 z; z.x = 0.f; z.y = 0.f;
    for (int cc = threadIdx.x; cc < KK / 2; cc += 256)
        erow[cc] = (cc == half) ? one : z;
}

__global__ __launch_bounds__(256) void fin_kernel(const int* __restrict__ hist,
                                                  const double* __restrict__ loss_acc,
                                                  float* __restrict__ out) {
    __shared__ double red[256];
    int tid = threadIdx.x;
    double s = 0.0;
    for (int k = tid; k < KK; k += 256) {
        double p = (double)hist[k] * (1.0 / 32768.0);
        s += p * log(p + 1e-10);
    }
    red[tid] = s;
    __syncthreads();
    for (int t = 128; t > 0; t >>= 1) {
        if (tid < t) red[tid] += red[tid + t];
        __syncthreads();
    }
    if (tid == 0) {
        double perp = exp(-red[0]);
        double L = loss_acc[0] * (1.0 / ((double)BB * (double)DD));
        out[LOSS_OFF] = (float)(1.25 * L);
        out[PERP_OFF] = (float)perp;
    }
}

extern "C" void kernel_launch(void* const* d_in, const int* in_sizes, int n_in,
                              void* d_out, int out_size, void* d_ws, size_t ws_size,
                              hipStream_t stream) {
    const float* X; const float* E;
    if (in_sizes[0] == BB * DD) { X = (const float*)d_in[0]; E = (const float*)d_in[1]; }
    else                        { X = (const float*)d_in[1]; E = (const float*)d_in[0]; }
    float* out = (float*)d_out;

    float* xsq = (float*)((char*)d_ws + WSB_XSQ);
    float* esq = (float*)((char*)d_ws + WSB_ESQ);
    int* idxbuf = (int*)((char*)d_ws + WSB_IDX);
    int* hist   = (int*)((char*)d_ws + WSB_HIST);
    double* loss_acc = (double*)((char*)d_ws + WSB_LOSS);
    char* Ei8 = (char*)d_ws + WSB_EI8;
    char* Xi8 = (char*)d_ws + WSB_XI8;
    uint2* partials = (uint2*)((char*)d_ws + WSB_PART);

    hipLaunchKernelGGL(npsum_pack_kernel, dim3((BB + KK) / 4), dim3(256), 0, stream,
                       X, E, xsq, esq, Xi8);
    hipLaunchKernelGGL(packEi8_kernel, dim3(512), dim3(256), 0, stream,
                       E, Ei8, hist, loss_acc);
    hipLaunchKernelGGL(iscreen, dim3(256), dim3(256), 0, stream,
                       Xi8, Ei8, partials);
    hipLaunchKernelGGL(reduce_kernel, dim3(BB / 256), dim3(256), 0, stream,
                       X, E, xsq, esq, partials, idxbuf, hist, loss_acc, out);
    hipLaunchKernelGGL(encq_kernel, dim3(BB), dim3(256), 0, stream, idxbuf, E, out);
    hipLaunchKernelGGL(fin_kernel, dim3(1), dim3(256), 0, stream, hist, loss_acc, out);
}

// Round 18
// 479.778 us; speedup vs baseline: 1.2936x; 1.2936x over previous
//
#include <hip/hip_runtime.h>
#include <hip/hip_bf16.h>

// VectorQuantizer B=32768, K=4096, D=512, fp32 in/out.
// Out concat (f32): quantized_st[B*512] | indices[B] | loss | perplexity | encodings[B*4096].
// R18: R13 base (best, 458us) + one-hot ZERO-FILL fused into the compute-bound
// gemm_screen (512MB of zeros written with idle BW; stream order gemm->reduce->encq
// guarantees zeros land before the 1.0s). encq slims to quantized gather + single
// one-hot pair per row. All screen/rescore/npsum math verbatim from R13.

typedef __attribute__((ext_vector_type(8))) short bf16x8;
typedef __attribute__((ext_vector_type(4))) float f32x4;

#define BB 32768
#define KK 4096
#define DD 512

#define IDX_OFF  (BB*DD)
#define LOSS_OFF (IDX_OFF + BB)
#define PERP_OFF (LOSS_OFF + 1)
#define ENC_OFF  (PERP_OFF + 1)

// ws byte offsets
#define WSB_XSQ  0
#define WSB_ESQ  131072
#define WSB_IDX  147456
#define WSB_HIST 278528
#define WSB_LOSS 294912
#define WSB_EBF2 294928          // 4 MB: E bf16, packed per (cb2,kt64) 32KB chunk
#define WSB_XBF  4489232         // 32 MB: X bf16, packed per (rb2,kt64) 32KB chunk
#define WSB_PART 38043664        // 16 MB: uint2 partials [64][32768]

#define MARG 2.5e-4f
#define NCAND 16

static __device__ __forceinline__ unsigned short f2bf(float f) {
    __hip_bfloat16 h = __float2bfloat16(f);
    return *reinterpret_cast<unsigned short*>(&h);
}

static __device__ __forceinline__ unsigned int packscore(float s, int col) {
    unsigned int u = __float_as_uint(s);
    u ^= (u & 0x80000000u) ? 0xFFFFFFFFu : 0x80000000u;
    return (u & 0xFFFFF000u) | (unsigned int)col;
}
static __device__ __forceinline__ float unpackscore(unsigned int p) {
    unsigned int u = p & 0xFFFFF000u;
    u = (u & 0x80000000u) ? (u ^ 0x80000000u) : ~u;
    return __uint_as_float(u);
}

static __device__ __forceinline__ void gll16(const void* g, void* l) {
    __builtin_amdgcn_global_load_lds(
        (const __attribute__((address_space(1))) unsigned int*)g,
        (__attribute__((address_space(3))) unsigned int*)l, 16, 0, 0);
}

// numpy-emulated row sum-of-squares (pairwise-128 + AVX512 lane fold; tree math
// bit-identical to R5-R17) FUSED with X bf16 fragment-packing (R13 layout).
__global__ __launch_bounds__(256) void npsum_pack_kernel(const float* __restrict__ X,
                                                         const float* __restrict__ E,
                                                         float* __restrict__ xsq,
                                                         float* __restrict__ esq,
                                                         unsigned short* __restrict__ Xbf) {
    __shared__ float sq[4][512];
    __shared__ float ub[4][64];
    __shared__ float bb[4][4];
    int w = threadIdx.x >> 6, lane = threadIdx.x & 63;
    int row = blockIdx.x * 4 + w;
    const float* src; float* dst;
    bool isx = (row < BB);
    if (isx) { src = X + (size_t)row * DD;        dst = xsq + row; }
    else     { src = E + (size_t)(row - BB) * DD; dst = esq + (row - BB); }
    const float4* s4 = (const float4*)(src + lane * 8);
    float4 a = s4[0], b = s4[1];
    sq[w][lane * 8 + 0] = __fmul_rn(a.x, a.x);
    sq[w][lane * 8 + 1] = __fmul_rn(a.y, a.y);
    sq[w][lane * 8 + 2] = __fmul_rn(a.z, a.z);
    sq[w][lane * 8 + 3] = __fmul_rn(a.w, a.w);
    sq[w][lane * 8 + 4] = __fmul_rn(b.x, b.x);
    sq[w][lane * 8 + 5] = __fmul_rn(b.y, b.y);
    sq[w][lane * 8 + 6] = __fmul_rn(b.z, b.z);
    sq[w][lane * 8 + 7] = __fmul_rn(b.w, b.w);
    if (isx) {   // emit Xbf fragment-packed unit for [row][lane*8 ..+7]
        int kt64 = lane >> 3, ks = (lane >> 2) & 1, oct = lane & 3;
        int rf = (row >> 4) & 15;
        size_t unit = ((size_t)((row >> 8) * 8 + kt64)) * 2048
                    + (size_t)((rf * 2 + ks) * 64 + oct * 16 + (row & 15));
        union { bf16x8 v; unsigned short us[8]; } pk;
        pk.us[0] = f2bf(a.x); pk.us[1] = f2bf(a.y); pk.us[2] = f2bf(a.z); pk.us[3] = f2bf(a.w);
        pk.us[4] = f2bf(b.x); pk.us[5] = f2bf(b.y); pk.us[6] = f2bf(b.z); pk.us[7] = f2bf(b.w);
        *(bf16x8*)(Xbf + unit * 8) = pk.v;
    }
    __syncthreads();
    {
        int b2 = lane >> 4, l = lane & 15;
        const float* s = &sq[w][b2 * 128];
        float t = __fadd_rn(
            __fadd_rn(__fadd_rn(s[l], s[16 + l]), __fadd_rn(s[32 + l], s[48 + l])),
            __fadd_rn(__fadd_rn(s[64 + l], s[80 + l]), __fadd_rn(s[96 + l], s[112 + l])));
        ub[w][lane] = t;
    }
    __syncthreads();
    if (lane < 4) {
        const float* u = &ub[w][lane * 16];
        float T3[8], T6[4];
        #pragma unroll
        for (int i = 0; i < 8; ++i) T3[i] = __fadd_rn(u[i], u[i + 8]);
        #pragma unroll
        for (int i = 0; i < 4; ++i) T6[i] = __fadd_rn(T3[i], T3[i + 4]);
        bb[w][lane] = __fadd_rn(__fadd_rn(T6[0], T6[2]), __fadd_rn(T6[1], T6[3]));
    }
    __syncthreads();
    if (lane == 0)
        *dst = __fadd_rn(__fadd_rn(bb[w][0], bb[w][1]), __fadd_rn(bb[w][2], bb[w][3]));
}

// E fp32 -> bf16 packed 32KB chunks (256 rows x 64 k), R13 layout. Fused init.
__global__ __launch_bounds__(256) void packE_kernel(const float* __restrict__ src,
                                                    unsigned short* __restrict__ dst,
                                                    int* __restrict__ hist,
                                                    double* __restrict__ loss_acc) {
    int t = blockIdx.x * 256 + threadIdx.x;
    if (t < KK) hist[t] = 0;
    if (t == KK) *loss_acc = 0.0;
    int chunk = t >> 11, u = t & 2047;
    int rb2 = chunk >> 3, kt = chunk & 7;
    int rf = u >> 7, ks = (u >> 6) & 1, lane = u & 63;
    int row = rb2 * 256 + rf * 16 + (lane & 15);
    int k   = kt * 64 + ks * 32 + (lane >> 4) * 8;
    const float4* s = (const float4*)(src + (size_t)row * DD + k);
    float4 a = s[0], b = s[1];
    union { bf16x8 v; unsigned short us[8]; } pk;
    pk.us[0] = f2bf(a.x); pk.us[1] = f2bf(a.y); pk.us[2] = f2bf(a.z); pk.us[3] = f2bf(a.w);
    pk.us[4] = f2bf(b.x); pk.us[5] = f2bf(b.y); pk.us[6] = f2bf(b.z); pk.us[7] = f2bf(b.w);
    *(bf16x8*)(dst + (size_t)t * 8) = pk.v;
}

// GEMM screen (R13 structure verbatim): 128^2 tile, BK=32, 32KB LDS, 4 blocks/CU.
// + fused background zero-fill of this block's 64KB one-hot slice.
__global__ __launch_bounds__(256, 4) void gemm_screen(
    const unsigned short* __restrict__ Xbf, const unsigned short* __restrict__ Ebf2,
    const float* __restrict__ esqw, uint2* __restrict__ partials,
    float* __restrict__ out)
{
    __shared__ __align__(16) char pool[32768];

    const int tid = threadIdx.x;
    const int w = tid >> 6, lane = tid & 63;
    const int c = lane & 15, g = lane >> 4;
    const int bid = blockIdx.x;
    const int orig = (bid & 7) * 1024 + (bid >> 3);   // bijective: 8192 % 8 == 0
    const int rb = orig >> 5, cb = orig & 31;
    const int row0 = rb * 128, col0 = cb * 128;
    const int mw = w >> 1, nw = w & 1;

    const int hA = rb & 1, hB = cb & 1;
    const char* Xc = (const char*)Xbf  + (size_t)(rb >> 1) * 8 * 32768;
    const char* Ec = (const char*)Ebf2 + (size_t)(cb >> 1) * 8 * 32768;

    f32x4 acc[4][4];
    #pragma unroll
    for (int i = 0; i < 4; ++i)
        #pragma unroll
        for (int j = 0; j < 4; ++j) acc[i][j] = (f32x4){0.f, 0.f, 0.f, 0.f};

    #define STAGE(srcc_, h_, kt_, dstoff_) { \
        const char* sb_ = (srcc_) + (size_t)((kt_) >> 1) * 32768; \
        const int ks_ = (kt_) & 1; \
        _Pragma("unroll") for (int it_ = 0; it_ < 2; ++it_) { \
            const char* s_ = sb_ + (size_t)((((h_) * 8 + it_ * 4 + w) * 2 + ks_) * 64 + lane) * 16; \
            char* d_ = pool + (dstoff_) + (it_ * 4 + w) * 1024; \
            gll16(s_, d_); } }

    STAGE(Xc, hA, 0, 0); STAGE(Ec, hB, 0, 16384);
    __syncthreads();
    int buf = 0;
    for (int kt = 0; kt < 16; ++kt) {
        if (kt < 15) {
            STAGE(Xc, hA, kt + 1, (buf ^ 1) * 8192);
            STAGE(Ec, hB, kt + 1, 16384 + (buf ^ 1) * 8192);
        }
        const char* Ap = pool + buf * 8192;
        const char* Bp = pool + 16384 + buf * 8192;
        bf16x8 af[4], bfr[4];
        #pragma unroll
        for (int i = 0; i < 4; ++i) {
            af[i]  = *(const bf16x8*)(Ap + (((mw * 4 + i) * 64) + lane) * 16);
            bfr[i] = *(const bf16x8*)(Bp + (((nw * 4 + i) * 64) + lane) * 16);
        }
        #pragma unroll
        for (int mf = 0; mf < 4; ++mf)
            #pragma unroll
            for (int nf = 0; nf < 4; ++nf)
                acc[mf][nf] = __builtin_amdgcn_mfma_f32_16x16x32_bf16(af[mf], bfr[nf], acc[mf][nf], 0, 0, 0);
        __syncthreads();
        buf ^= 1;
    }

    // epilogue: scores -> per-lane top2-of-4nf -> LDS -> per-(row,nw) top2 -> partials
    uint2* P = (uint2*)pool;   // [2][128][16] aliases pool after last barrier
    #pragma unroll
    for (int mf = 0; mf < 4; ++mf) {
        #pragma unroll
        for (int r = 0; r < 4; ++r) {
            unsigned int q1 = 0xFFFFFFFFu, q2 = 0xFFFFFFFFu;
            int rowl = mw * 64 + mf * 16 + g * 4 + r;
            #pragma unroll
            for (int nf = 0; nf < 4; ++nf) {
                int col = col0 + nw * 64 + nf * 16 + c;
                float s = fmaf(-2.0f, acc[mf][nf][r], esqw[col]);
                unsigned int q = packscore(s, col);
                if (q < q1) { q2 = q1; q1 = q; } else if (q < q2) q2 = q;
            }
            P[(nw * 128 + rowl) * 16 + c] = make_uint2(q1, q2);
        }
    }
    __syncthreads();
    if (tid < 128) {
        int row = tid;
        #pragma unroll
        for (int n2 = 0; n2 < 2; ++n2) {
            unsigned int m1 = 0xFFFFFFFFu, m2 = 0xFFFFFFFFu;
            #pragma unroll 4
            for (int cc = 0; cc < 16; ++cc) {
                uint2 e = P[(n2 * 128 + row) * 16 + cc];
                if (e.x < m1) { m2 = m1; m1 = e.x; } else if (e.x < m2) m2 = e.x;
                if (e.y < m1) { m2 = m1; m1 = e.y; } else if (e.y < m2) m2 = e.y;
            }
            partials[(size_t)(cb * 2 + n2) * BB + row0 + row] = make_uint2(m1, m2);
        }
    }
    // fused background zero-fill: this block's 16384-f32 slice of the one-hot
    // region (stream order guarantees encq's 1.0 writes land after).
    {
        float2* z = (float2*)(out + ENC_OFF) + (size_t)bid * 8192;
        float2 zz; zz.x = 0.f; zz.y = 0.f;
        #pragma unroll
        for (int j = 0; j < 32; ++j) z[tid + j * 256] = zz;
    }
    #undef STAGE
}

// merge partials -> candidates -> numpy-fp32 rescore -> idx/hist/loss (verbatim R11-R17)
__global__ __launch_bounds__(256) void reduce_kernel(
    const float* __restrict__ X, const float* __restrict__ E,
    const float* __restrict__ xsqw, const float* __restrict__ esqw,
    const uint2* __restrict__ partials, int* __restrict__ idxbuf,
    int* __restrict__ hist, double* __restrict__ loss_acc,
    float* __restrict__ out)
{
    __shared__ double lred[256];
    const int row = blockIdx.x * 256 + threadIdx.x;
    unsigned int m = 0xFFFFFFFFu;
    for (int e = 0; e < 64; ++e) m = min(m, partials[(size_t)e * BB + row].x);
    float lim = unpackscore(m) + MARG;
    int cand[NCAND]; int nc = 0;
    for (int e = 0; e < 64; ++e) {
        uint2 p = partials[(size_t)e * BB + row];
        if (unpackscore(p.x) <= lim && nc < NCAND) cand[nc++] = (int)(p.x & 0xFFFu);
        if (unpackscore(p.y) <= lim && nc < NCAND) cand[nc++] = (int)(p.y & 0xFFFu);
    }
    const float* xr = X + (size_t)row * DD;
    float xs = xsqw[row];
    float bd = 3.0e38f; int bk = 0x7fffffff;
    for (int cidx = 0; cidx < nc; ++cidx) {
        int k = cand[cidx] & (KK - 1);
        const float* er = E + (size_t)k * DD;
        float q1 = 0.f, q2 = 0.f;
        for (int d = 0; d < 384; ++d)   q1 = fmaf(xr[d], er[d], q1);
        for (int d = 384; d < 512; ++d) q2 = fmaf(xr[d], er[d], q2);
        float dot = __fadd_rn(q1, q2);
        float t1  = __fadd_rn(xs, esqw[k]);
        float dnp = __fsub_rn(t1, __fmul_rn(2.0f, dot));
        if (dnp < bd || (dnp == bd && k < bk)) { bd = dnp; bk = k; }
    }
    const float* er = E + (size_t)bk * DD;
    double ls = 0.0;
    for (int d = 0; d < DD; ++d) {
        double df = (double)xr[d] - (double)er[d];
        ls = fma(df, df, ls);
    }
    idxbuf[row] = bk;
    out[IDX_OFF + row] = (float)bk;
    atomicAdd(&hist[bk], 1);
    lred[threadIdx.x] = ls;
    __syncthreads();
    for (int t = 128; t > 0; t >>= 1) {
        if (threadIdx.x < t) lred[threadIdx.x] += lred[threadIdx.x + t];
        __syncthreads();
    }
    if (threadIdx.x == 0) atomicAdd(loss_acc, lred[0]);
}

// one block per row: quantized gather (coalesced) + SINGLE one-hot pair write
// (zeros already laid down by gemm_screen's fused fill).
__global__ __launch_bounds__(256) void encq_kernel(const int* __restrict__ idxbuf,
                                                   const float* __restrict__ E,
                                                   float* __restrict__ out) {
    int row = blockIdx.x;
    int idx = idxbuf[row];
    ((float2*)out)[(size_t)row * 256 + threadIdx.x] =
        ((const float2*)E)[(size_t)idx * 256 + threadIdx.x];
    if (threadIdx.x == 0) {
        float2 one;
        if (idx & 1) { one.x = 0.f; one.y = 1.f; } else { one.x = 1.f; one.y = 0.f; }
        ((float2*)(out + ENC_OFF))[(size_t)row * (KK / 2) + (idx >> 1)] = one;
    }
}

__global__ __launch_bounds__(256) void fin_kernel(const int* __restrict__ hist,
                                                  const double* __restrict__ loss_acc,
                                                  float* __restrict__ out) {
    __shared__ double red[256];
    int tid = threadIdx.x;
    double s = 0.0;
    for (int k = tid; k < KK; k += 256) {
        double p = (double)hist[k] * (1.0 / 32768.0);
        s += p * log(p + 1e-10);
    }
    red[tid] = s;
    __syncthreads();
    for (int t = 128; t > 0; t >>= 1) {
        if (tid < t) red[tid] += red[tid + t];
        __syncthreads();
    }
    if (tid == 0) {
        double perp = exp(-red[0]);
        double L = loss_acc[0] * (1.0 / ((double)BB * (double)DD));
        out[LOSS_OFF] = (float)(1.25 * L);
        out[PERP_OFF] = (float)perp;
    }
}

extern "C" void kernel_launch(void* const* d_in, const int* in_sizes, int n_in,
                              void* d_out, int out_size, void* d_ws, size_t ws_size,
                              hipStream_t stream) {
    const float* X; const float* E;
    if (in_sizes[0] == BB * DD) { X = (const float*)d_in[0]; E = (const float*)d_in[1]; }
    else                        { X = (const float*)d_in[1]; E = (const float*)d_in[0]; }
    float* out = (float*)d_out;

    float* xsq = (float*)((char*)d_ws + WSB_XSQ);
    float* esq = (float*)((char*)d_ws + WSB_ESQ);
    int* idxbuf = (int*)((char*)d_ws + WSB_IDX);
    int* hist   = (int*)((char*)d_ws + WSB_HIST);
    double* loss_acc = (double*)((char*)d_ws + WSB_LOSS);
    unsigned short* Ebf2 = (unsigned short*)((char*)d_ws + WSB_EBF2);
    unsigned short* Xbf  = (unsigned short*)((char*)d_ws + WSB_XBF);
    uint2* partials = (uint2*)((char*)d_ws + WSB_PART);

    hipLaunchKernelGGL(npsum_pack_kernel, dim3((BB + KK) / 4), dim3(256), 0, stream,
                       X, E, xsq, esq, Xbf);
    hipLaunchKernelGGL(packE_kernel, dim3(1024), dim3(256), 0, stream,
                       E, Ebf2, hist, loss_acc);
    hipLaunchKernelGGL(gemm_screen, dim3(8192), dim3(256), 0, stream,
                       Xbf, Ebf2, esq, partials, out);
    hipLaunchKernelGGL(reduce_kernel, dim3(BB / 256), dim3(256), 0, stream,
                       X, E, xsq, esq, partials, idxbuf, hist, loss_acc, out);
    hipLaunchKernelGGL(encq_kernel, dim3(BB), dim3(256), 0, stream, idxbuf, E, out);
    hipLaunchKernelGGL(fin_kernel, dim3(1), dim3(256), 0, stream, hist, loss_acc, out);
}

// Round 19
// 453.077 us; speedup vs baseline: 1.3698x; 1.0589x over previous
//
#include <hip/hip_runtime.h>
#include <hip/hip_bf16.h>

// VectorQuantizer B=32768, K=4096, D=512, fp32 in/out.
// Out concat (f32): quantized_st[B*512] | indices[B] | loss | perplexity | encodings[B*4096].
// R19: R13 (best, 458us) with ONE change: the K-loop's __syncthreads (vmcnt(0)
// drain) replaced by issue-first + counted s_waitcnt vmcnt(4) + raw s_barrier
// pairs (T3/T4 minimal recipe). Prefetch stays in flight across barriers; each
// wave waits only the PREVIOUS tile's 4 gll16s. All math verbatim R13.

typedef __attribute__((ext_vector_type(8))) short bf16x8;
typedef __attribute__((ext_vector_type(4))) float f32x4;

#define BB 32768
#define KK 4096
#define DD 512

#define IDX_OFF  (BB*DD)
#define LOSS_OFF (IDX_OFF + BB)
#define PERP_OFF (LOSS_OFF + 1)
#define ENC_OFF  (PERP_OFF + 1)

// ws byte offsets
#define WSB_XSQ  0
#define WSB_ESQ  131072
#define WSB_IDX  147456
#define WSB_HIST 278528
#define WSB_LOSS 294912
#define WSB_EBF2 294928          // 4 MB: E bf16, packed per (cb2,kt64) 32KB chunk
#define WSB_XBF  4489232         // 32 MB: X bf16, packed per (rb2,kt64) 32KB chunk
#define WSB_PART 38043664        // 16 MB: uint2 partials [64][32768]

#define MARG 2.5e-4f
#define NCAND 16

static __device__ __forceinline__ unsigned short f2bf(float f) {
    __hip_bfloat16 h = __float2bfloat16(f);
    return *reinterpret_cast<unsigned short*>(&h);
}

static __device__ __forceinline__ unsigned int packscore(float s, int col) {
    unsigned int u = __float_as_uint(s);
    u ^= (u & 0x80000000u) ? 0xFFFFFFFFu : 0x80000000u;
    return (u & 0xFFFFF000u) | (unsigned int)col;
}
static __device__ __forceinline__ float unpackscore(unsigned int p) {
    unsigned int u = p & 0xFFFFF000u;
    u = (u & 0x80000000u) ? (u ^ 0x80000000u) : ~u;
    return __uint_as_float(u);
}

static __device__ __forceinline__ void gll16(const void* g, void* l) {
    __builtin_amdgcn_global_load_lds(
        (const __attribute__((address_space(1))) unsigned int*)g,
        (__attribute__((address_space(3))) unsigned int*)l, 16, 0, 0);
}

__global__ __launch_bounds__(256) void init_kernel(int* __restrict__ hist,
                                                   double* __restrict__ loss_acc) {
    int i = blockIdx.x * 256 + threadIdx.x;
    if (i < KK) hist[i] = 0;
    if (i == 0) *loss_acc = 0.0;
}

// numpy-emulated row sum-of-squares (pairwise-128 + AVX512 lane fold; tree math
// bit-identical to R5-R18) FUSED with X bf16 fragment-packing (R13 layout).
__global__ __launch_bounds__(256) void npsum_pack_kernel(const float* __restrict__ X,
                                                         const float* __restrict__ E,
                                                         float* __restrict__ xsq,
                                                         float* __restrict__ esq,
                                                         unsigned short* __restrict__ Xbf) {
    __shared__ float sq[4][512];
    __shared__ float ub[4][64];
    __shared__ float bb[4][4];
    int w = threadIdx.x >> 6, lane = threadIdx.x & 63;
    int row = blockIdx.x * 4 + w;
    const float* src; float* dst;
    bool isx = (row < BB);
    if (isx) { src = X + (size_t)row * DD;        dst = xsq + row; }
    else     { src = E + (size_t)(row - BB) * DD; dst = esq + (row - BB); }
    const float4* s4 = (const float4*)(src + lane * 8);
    float4 a = s4[0], b = s4[1];
    sq[w][lane * 8 + 0] = __fmul_rn(a.x, a.x);
    sq[w][lane * 8 + 1] = __fmul_rn(a.y, a.y);
    sq[w][lane * 8 + 2] = __fmul_rn(a.z, a.z);
    sq[w][lane * 8 + 3] = __fmul_rn(a.w, a.w);
    sq[w][lane * 8 + 4] = __fmul_rn(b.x, b.x);
    sq[w][lane * 8 + 5] = __fmul_rn(b.y, b.y);
    sq[w][lane * 8 + 6] = __fmul_rn(b.z, b.z);
    sq[w][lane * 8 + 7] = __fmul_rn(b.w, b.w);
    if (isx) {   // emit Xbf fragment-packed unit for [row][lane*8 ..+7]
        int kt64 = lane >> 3, ks = (lane >> 2) & 1, oct = lane & 3;
        int rf = (row >> 4) & 15;
        size_t unit = ((size_t)((row >> 8) * 8 + kt64)) * 2048
                    + (size_t)((rf * 2 + ks) * 64 + oct * 16 + (row & 15));
        union { bf16x8 v; unsigned short us[8]; } pk;
        pk.us[0] = f2bf(a.x); pk.us[1] = f2bf(a.y); pk.us[2] = f2bf(a.z); pk.us[3] = f2bf(a.w);
        pk.us[4] = f2bf(b.x); pk.us[5] = f2bf(b.y); pk.us[6] = f2bf(b.z); pk.us[7] = f2bf(b.w);
        *(bf16x8*)(Xbf + unit * 8) = pk.v;
    }
    __syncthreads();
    {
        int b2 = lane >> 4, l = lane & 15;
        const float* s = &sq[w][b2 * 128];
        float t = __fadd_rn(
            __fadd_rn(__fadd_rn(s[l], s[16 + l]), __fadd_rn(s[32 + l], s[48 + l])),
            __fadd_rn(__fadd_rn(s[64 + l], s[80 + l]), __fadd_rn(s[96 + l], s[112 + l])));
        ub[w][lane] = t;
    }
    __syncthreads();
    if (lane < 4) {
        const float* u = &ub[w][lane * 16];
        float T3[8], T6[4];
        #pragma unroll
        for (int i = 0; i < 8; ++i) T3[i] = __fadd_rn(u[i], u[i + 8]);
        #pragma unroll
        for (int i = 0; i < 4; ++i) T6[i] = __fadd_rn(T3[i], T3[i + 4]);
        bb[w][lane] = __fadd_rn(__fadd_rn(T6[0], T6[2]), __fadd_rn(T6[1], T6[3]));
    }
    __syncthreads();
    if (lane == 0)
        *dst = __fadd_rn(__fadd_rn(bb[w][0], bb[w][1]), __fadd_rn(bb[w][2], bb[w][3]));
}

// E fp32 -> bf16 packed 32KB chunks (256 rows x 64 k), R13 layout.
__global__ __launch_bounds__(256) void packE_kernel(const float* __restrict__ src,
                                                    unsigned short* __restrict__ dst) {
    int t = blockIdx.x * 256 + threadIdx.x;
    int chunk = t >> 11, u = t & 2047;
    int rb2 = chunk >> 3, kt = chunk & 7;
    int rf = u >> 7, ks = (u >> 6) & 1, lane = u & 63;
    int row = rb2 * 256 + rf * 16 + (lane & 15);
    int k   = kt * 64 + ks * 32 + (lane >> 4) * 8;
    const float4* s = (const float4*)(src + (size_t)row * DD + k);
    float4 a = s[0], b = s[1];
    union { bf16x8 v; unsigned short us[8]; } pk;
    pk.us[0] = f2bf(a.x); pk.us[1] = f2bf(a.y); pk.us[2] = f2bf(a.z); pk.us[3] = f2bf(a.w);
    pk.us[4] = f2bf(b.x); pk.us[5] = f2bf(b.y); pk.us[6] = f2bf(b.z); pk.us[7] = f2bf(b.w);
    *(bf16x8*)(dst + (size_t)t * 8) = pk.v;
}

// GEMM screen: R13 structure (128^2 tile, BK=32, 32KB LDS, 4 blocks/CU) with
// counted-vmcnt K-loop: issue-first, s_waitcnt vmcnt(4), raw s_barrier pairs.
__global__ __launch_bounds__(256, 4) void gemm_screen(
    const unsigned short* __restrict__ Xbf, const unsigned short* __restrict__ Ebf2,
    const float* __restrict__ esqw, uint2* __restrict__ partials)
{
    __shared__ __align__(16) char pool[32768];

    const int tid = threadIdx.x;
    const int w = tid >> 6, lane = tid & 63;
    const int c = lane & 15, g = lane >> 4;
    const int bid = blockIdx.x;
    const int orig = (bid & 7) * 1024 + (bid >> 3);   // bijective: 8192 % 8 == 0
    const int rb = orig >> 5, cb = orig & 31;
    const int row0 = rb * 128, col0 = cb * 128;
    const int mw = w >> 1, nw = w & 1;

    const int hA = rb & 1, hB = cb & 1;
    const char* Xc = (const char*)Xbf  + (size_t)(rb >> 1) * 8 * 32768;
    const char* Ec = (const char*)Ebf2 + (size_t)(cb >> 1) * 8 * 32768;

    f32x4 acc[4][4];
    #pragma unroll
    for (int i = 0; i < 4; ++i)
        #pragma unroll
        for (int j = 0; j < 4; ++j) acc[i][j] = (f32x4){0.f, 0.f, 0.f, 0.f};

    // stage 8KB = 128 rows x 32 k: 2 gll16 per thread
    #define STAGE(srcc_, h_, kt_, dstoff_) { \
        const char* sb_ = (srcc_) + (size_t)((kt_) >> 1) * 32768; \
        const int ks_ = (kt_) & 1; \
        _Pragma("unroll") for (int it_ = 0; it_ < 2; ++it_) { \
            const char* s_ = sb_ + (size_t)((((h_) * 8 + it_ * 4 + w) * 2 + ks_) * 64 + lane) * 16; \
            char* d_ = pool + (dstoff_) + (it_ * 4 + w) * 1024; \
            gll16(s_, d_); } }

    STAGE(Xc, hA, 0, 0); STAGE(Ec, hB, 0, 16384);   // 4 gll16 in flight (tile 0)
    int buf = 0;
    for (int kt = 0; kt < 16; ++kt) {
        if (kt < 15) {
            // issue next tile FIRST (4 gll16), then wait only for tile kt's 4
            STAGE(Xc, hA, kt + 1, (buf ^ 1) * 8192);
            STAGE(Ec, hB, kt + 1, 16384 + (buf ^ 1) * 8192);
            asm volatile("s_waitcnt vmcnt(4)" ::: "memory");
        } else {
            asm volatile("s_waitcnt vmcnt(0)" ::: "memory");
        }
        __builtin_amdgcn_s_barrier();   // all waves' tile-kt data resident
        const char* Ap = pool + buf * 8192;
        const char* Bp = pool + 16384 + buf * 8192;
        bf16x8 af[4], bfr[4];
        #pragma unroll
        for (int i = 0; i < 4; ++i) {
            af[i]  = *(const bf16x8*)(Ap + (((mw * 4 + i) * 64) + lane) * 16);
            bfr[i] = *(const bf16x8*)(Bp + (((nw * 4 + i) * 64) + lane) * 16);
        }
        __builtin_amdgcn_s_setprio(1);
        #pragma unroll
        for (int mf = 0; mf < 4; ++mf)
            #pragma unroll
            for (int nf = 0; nf < 4; ++nf)
                acc[mf][nf] = __builtin_amdgcn_mfma_f32_16x16x32_bf16(af[mf], bfr[nf], acc[mf][nf], 0, 0, 0);
        __builtin_amdgcn_s_setprio(0);
        __builtin_amdgcn_s_barrier();   // reads of buf done before next overwrite
        buf ^= 1;
    }

    // epilogue: scores -> per-lane top2-of-4nf -> LDS -> per-(row,nw) top2 -> partials
    uint2* P = (uint2*)pool;   // aliases pool after final barrier
    #pragma unroll
    for (int mf = 0; mf < 4; ++mf) {
        #pragma unroll
        for (int r = 0; r < 4; ++r) {
            unsigned int q1 = 0xFFFFFFFFu, q2 = 0xFFFFFFFFu;
            int rowl = mw * 64 + mf * 16 + g * 4 + r;
            #pragma unroll
            for (int nf = 0; nf < 4; ++nf) {
                int col = col0 + nw * 64 + nf * 16 + c;
                float s = fmaf(-2.0f, acc[mf][nf][r], esqw[col]);
                unsigned int q = packscore(s, col);
                if (q < q1) { q2 = q1; q1 = q; } else if (q < q2) q2 = q;
            }
            P[(nw * 128 + rowl) * 16 + c] = make_uint2(q1, q2);
        }
    }
    __syncthreads();
    if (tid < 128) {
        int row = tid;
        #pragma unroll
        for (int n2 = 0; n2 < 2; ++n2) {
            unsigned int m1 = 0xFFFFFFFFu, m2 = 0xFFFFFFFFu;
            #pragma unroll 4
            for (int cc = 0; cc < 16; ++cc) {
                uint2 e = P[(n2 * 128 + row) * 16 + cc];
                if (e.x < m1) { m2 = m1; m1 = e.x; } else if (e.x < m2) m2 = e.x;
                if (e.y < m1) { m2 = m1; m1 = e.y; } else if (e.y < m2) m2 = e.y;
            }
            partials[(size_t)(cb * 2 + n2) * BB + row0 + row] = make_uint2(m1, m2);
        }
    }
    #undef STAGE
}

// merge partials -> candidates -> numpy-fp32 rescore -> idx/hist/loss (verbatim R11-R18)
__global__ __launch_bounds__(256) void reduce_kernel(
    const float* __restrict__ X, const float* __restrict__ E,
    const float* __restrict__ xsqw, const float* __restrict__ esqw,
    const uint2* __restrict__ partials, int* __restrict__ idxbuf,
    int* __restrict__ hist, double* __restrict__ loss_acc,
    float* __restrict__ out)
{
    __shared__ double lred[256];
    const int row = blockIdx.x * 256 + threadIdx.x;
    unsigned int m = 0xFFFFFFFFu;
    for (int e = 0; e < 64; ++e) m = min(m, partials[(size_t)e * BB + row].x);
    float lim = unpackscore(m) + MARG;
    int cand[NCAND]; int nc = 0;
    for (int e = 0; e < 64; ++e) {
        uint2 p = partials[(size_t)e * BB + row];
        if (unpackscore(p.x) <= lim && nc < NCAND) cand[nc++] = (int)(p.x & 0xFFFu);
        if (unpackscore(p.y) <= lim && nc < NCAND) cand[nc++] = (int)(p.y & 0xFFFu);
    }
    const float* xr = X + (size_t)row * DD;
    float xs = xsqw[row];
    float bd = 3.0e38f; int bk = 0x7fffffff;
    for (int cidx = 0; cidx < nc; ++cidx) {
        int k = cand[cidx] & (KK - 1);
        const float* er = E + (size_t)k * DD;
        float q1 = 0.f, q2 = 0.f;
        for (int d = 0; d < 384; ++d)   q1 = fmaf(xr[d], er[d], q1);
        for (int d = 384; d < 512; ++d) q2 = fmaf(xr[d], er[d], q2);
        float dot = __fadd_rn(q1, q2);
        float t1  = __fadd_rn(xs, esqw[k]);
        float dnp = __fsub_rn(t1, __fmul_rn(2.0f, dot));
        if (dnp < bd || (dnp == bd && k < bk)) { bd = dnp; bk = k; }
    }
    const float* er = E + (size_t)bk * DD;
    double ls = 0.0;
    for (int d = 0; d < DD; ++d) {
        double df = (double)xr[d] - (double)er[d];
        ls = fma(df, df, ls);
    }
    idxbuf[row] = bk;
    out[IDX_OFF + row] = (float)bk;
    atomicAdd(&hist[bk], 1);
    lred[threadIdx.x] = ls;
    __syncthreads();
    for (int t = 128; t > 0; t >>= 1) {
        if (threadIdx.x < t) lred[threadIdx.x] += lred[threadIdx.x + t];
        __syncthreads();
    }
    if (threadIdx.x == 0) atomicAdd(loss_acc, lred[0]);
}

// one block per row: quantized gather (coalesced) + one-hot row (verbatim R13)
__global__ __launch_bounds__(256) void encq_kernel(const int* __restrict__ idxbuf,
                                                   const float* __restrict__ E,
                                                   float* __restrict__ out) {
    int row = blockIdx.x;
    int idx = idxbuf[row];
    ((float2*)out)[(size_t)row * 256 + threadIdx.x] =
        ((const float2*)E)[(size_t)idx * 256 + threadIdx.x];
    float2* erow = (float2*)(out + ENC_OFF) + (size_t)row * (KK / 2);
    int half = idx >> 1;
    float2 one;
    if (idx & 1) { one.x = 0.f; one.y = 1.f; } else { one.x = 1.f; one.y = 0.f; }
    float2 z; z.x = 0.f; z.y = 0.f;
    for (int cc = threadIdx.x; cc < KK / 2; cc += 256)
        erow[cc] = (cc == half) ? one : z;
}

__global__ __launch_bounds__(256) void fin_kernel(const int* __restrict__ hist,
                                                  const double* __restrict__ loss_acc,
                                                  float* __restrict__ out) {
    __shared__ double red[256];
    int tid = threadIdx.x;
    double s = 0.0;
    for (int k = tid; k < KK; k += 256) {
        double p = (double)hist[k] * (1.0 / 32768.0);
        s += p * log(p + 1e-10);
    }
    red[tid] = s;
    __syncthreads();
    for (int t = 128; t > 0; t >>= 1) {
        if (tid < t) red[tid] += red[tid + t];
        __syncthreads();
    }
    if (tid == 0) {
        double perp = exp(-red[0]);
        double L = loss_acc[0] * (1.0 / ((double)BB * (double)DD));
        out[LOSS_OFF] = (float)(1.25 * L);
        out[PERP_OFF] = (float)perp;
    }
}

extern "C" void kernel_launch(void* const* d_in, const int* in_sizes, int n_in,
                              void* d_out, int out_size, void* d_ws, size_t ws_size,
                              hipStream_t stream) {
    const float* X; const float* E;
    if (in_sizes[0] == BB * DD) { X = (const float*)d_in[0]; E = (const float*)d_in[1]; }
    else                        { X = (const float*)d_in[1]; E = (const float*)d_in[0]; }
    float* out = (float*)d_out;

    float* xsq = (float*)((char*)d_ws + WSB_XSQ);
    float* esq = (float*)((char*)d_ws + WSB_ESQ);
    int* idxbuf = (int*)((char*)d_ws + WSB_IDX);
    int* hist   = (int*)((char*)d_ws + WSB_HIST);
    double* loss_acc = (double*)((char*)d_ws + WSB_LOSS);
    unsigned short* Ebf2 = (unsigned short*)((char*)d_ws + WSB_EBF2);
    unsigned short* Xbf  = (unsigned short*)((char*)d_ws + WSB_XBF);
    uint2* partials = (uint2*)((char*)d_ws + WSB_PART);

    hipLaunchKernelGGL(init_kernel, dim3(16), dim3(256), 0, stream, hist, loss_acc);
    hipLaunchKernelGGL(npsum_pack_kernel, dim3((BB + KK) / 4), dim3(256), 0, stream,
                       X, E, xsq, esq, Xbf);
    hipLaunchKernelGGL(packE_kernel, dim3(1024), dim3(256), 0, stream, E, Ebf2);
    hipLaunchKernelGGL(gemm_screen, dim3(8192), dim3(256), 0, stream,
                       Xbf, Ebf2, esq, partials);
    hipLaunchKernelGGL(reduce_kernel, dim3(BB / 256), dim3(256), 0, stream,
                       X, E, xsq, esq, partials, idxbuf, hist, loss_acc, out);
    hipLaunchKernelGGL(encq_kernel, dim3(BB), dim3(256), 0, stream, idxbuf, E, out);
    hipLaunchKernelGGL(fin_kernel, dim3(1), dim3(256), 0, stream, hist, loss_acc, out);
}

// Round 20
// 444.373 us; speedup vs baseline: 1.3966x; 1.0196x over previous
//
#include <hip/hip_runtime.h>
#include <hip/hip_bf16.h>

// VectorQuantizer B=32768, K=4096, D=512, fp32 in/out.
// Out concat (f32): quantized_st[B*512] | indices[B] | loss | perplexity | encodings[B*4096].
// R20: R19 (best, 453us) + fused finalize kernel (reduce+encq in one launch,
// 1024 blocks x 256 thr: 32 rescores by lanes 0-31, then block-wide coalesced
// quantized-gather + one-hot writes). init fused into packE. Screen verbatim R19.

typedef __attribute__((ext_vector_type(8))) short bf16x8;
typedef __attribute__((ext_vector_type(4))) float f32x4;

#define BB 32768
#define KK 4096
#define DD 512

#define IDX_OFF  (BB*DD)
#define LOSS_OFF (IDX_OFF + BB)
#define PERP_OFF (LOSS_OFF + 1)
#define ENC_OFF  (PERP_OFF + 1)

// ws byte offsets
#define WSB_XSQ  0
#define WSB_ESQ  131072
#define WSB_HIST 278528
#define WSB_LOSS 294912
#define WSB_EBF2 294928          // 4 MB: E bf16, packed per (cb2,kt64) 32KB chunk
#define WSB_XBF  4489232         // 32 MB: X bf16, packed per (rb2,kt64) 32KB chunk
#define WSB_PART 38043664        // 16 MB: uint2 partials [64][32768]

#define MARG 2.5e-4f
#define NCAND 16

static __device__ __forceinline__ unsigned short f2bf(float f) {
    __hip_bfloat16 h = __float2bfloat16(f);
    return *reinterpret_cast<unsigned short*>(&h);
}

static __device__ __forceinline__ unsigned int packscore(float s, int col) {
    unsigned int u = __float_as_uint(s);
    u ^= (u & 0x80000000u) ? 0xFFFFFFFFu : 0x80000000u;
    return (u & 0xFFFFF000u) | (unsigned int)col;
}
static __device__ __forceinline__ float unpackscore(unsigned int p) {
    unsigned int u = p & 0xFFFFF000u;
    u = (u & 0x80000000u) ? (u ^ 0x80000000u) : ~u;
    return __uint_as_float(u);
}

static __device__ __forceinline__ void gll16(const void* g, void* l) {
    __builtin_amdgcn_global_load_lds(
        (const __attribute__((address_space(1))) unsigned int*)g,
        (__attribute__((address_space(3))) unsigned int*)l, 16, 0, 0);
}

// numpy-emulated row sum-of-squares (pairwise-128 + AVX512 lane fold; tree math
// bit-identical to R5-R19) FUSED with X bf16 fragment-packing (R13 layout).
__global__ __launch_bounds__(256) void npsum_pack_kernel(const float* __restrict__ X,
                                                         const float* __restrict__ E,
                                                         float* __restrict__ xsq,
                                                         float* __restrict__ esq,
                                                         unsigned short* __restrict__ Xbf) {
    __shared__ float sq[4][512];
    __shared__ float ub[4][64];
    __shared__ float bb[4][4];
    int w = threadIdx.x >> 6, lane = threadIdx.x & 63;
    int row = blockIdx.x * 4 + w;
    const float* src; float* dst;
    bool isx = (row < BB);
    if (isx) { src = X + (size_t)row * DD;        dst = xsq + row; }
    else     { src = E + (size_t)(row - BB) * DD; dst = esq + (row - BB); }
    const float4* s4 = (const float4*)(src + lane * 8);
    float4 a = s4[0], b = s4[1];
    sq[w][lane * 8 + 0] = __fmul_rn(a.x, a.x);
    sq[w][lane * 8 + 1] = __fmul_rn(a.y, a.y);
    sq[w][lane * 8 + 2] = __fmul_rn(a.z, a.z);
    sq[w][lane * 8 + 3] = __fmul_rn(a.w, a.w);
    sq[w][lane * 8 + 4] = __fmul_rn(b.x, b.x);
    sq[w][lane * 8 + 5] = __fmul_rn(b.y, b.y);
    sq[w][lane * 8 + 6] = __fmul_rn(b.z, b.z);
    sq[w][lane * 8 + 7] = __fmul_rn(b.w, b.w);
    if (isx) {   // emit Xbf fragment-packed unit for [row][lane*8 ..+7]
        int kt64 = lane >> 3, ks = (lane >> 2) & 1, oct = lane & 3;
        int rf = (row >> 4) & 15;
        size_t unit = ((size_t)((row >> 8) * 8 + kt64)) * 2048
                    + (size_t)((rf * 2 + ks) * 64 + oct * 16 + (row & 15));
        union { bf16x8 v; unsigned short us[8]; } pk;
        pk.us[0] = f2bf(a.x); pk.us[1] = f2bf(a.y); pk.us[2] = f2bf(a.z); pk.us[3] = f2bf(a.w);
        pk.us[4] = f2bf(b.x); pk.us[5] = f2bf(b.y); pk.us[6] = f2bf(b.z); pk.us[7] = f2bf(b.w);
        *(bf16x8*)(Xbf + unit * 8) = pk.v;
    }
    __syncthreads();
    {
        int b2 = lane >> 4, l = lane & 15;
        const float* s = &sq[w][b2 * 128];
        float t = __fadd_rn(
            __fadd_rn(__fadd_rn(s[l], s[16 + l]), __fadd_rn(s[32 + l], s[48 + l])),
            __fadd_rn(__fadd_rn(s[64 + l], s[80 + l]), __fadd_rn(s[96 + l], s[112 + l])));
        ub[w][lane] = t;
    }
    __syncthreads();
    if (lane < 4) {
        const float* u = &ub[w][lane * 16];
        float T3[8], T6[4];
        #pragma unroll
        for (int i = 0; i < 8; ++i) T3[i] = __fadd_rn(u[i], u[i + 8]);
        #pragma unroll
        for (int i = 0; i < 4; ++i) T6[i] = __fadd_rn(T3[i], T3[i + 4]);
        bb[w][lane] = __fadd_rn(__fadd_rn(T6[0], T6[2]), __fadd_rn(T6[1], T6[3]));
    }
    __syncthreads();
    if (lane == 0)
        *dst = __fadd_rn(__fadd_rn(bb[w][0], bb[w][1]), __fadd_rn(bb[w][2], bb[w][3]));
}

// E fp32 -> bf16 packed 32KB chunks (256 rows x 64 k), R13 layout. Fused init.
__global__ __launch_bounds__(256) void packE_kernel(const float* __restrict__ src,
                                                    unsigned short* __restrict__ dst,
                                                    int* __restrict__ hist,
                                                    double* __restrict__ loss_acc) {
    int t = blockIdx.x * 256 + threadIdx.x;
    if (t < KK) hist[t] = 0;
    if (t == KK) *loss_acc = 0.0;
    int chunk = t >> 11, u = t & 2047;
    int rb2 = chunk >> 3, kt = chunk & 7;
    int rf = u >> 7, ks = (u >> 6) & 1, lane = u & 63;
    int row = rb2 * 256 + rf * 16 + (lane & 15);
    int k   = kt * 64 + ks * 32 + (lane >> 4) * 8;
    const float4* s = (const float4*)(src + (size_t)row * DD + k);
    float4 a = s[0], b = s[1];
    union { bf16x8 v; unsigned short us[8]; } pk;
    pk.us[0] = f2bf(a.x); pk.us[1] = f2bf(a.y); pk.us[2] = f2bf(a.z); pk.us[3] = f2bf(a.w);
    pk.us[4] = f2bf(b.x); pk.us[5] = f2bf(b.y); pk.us[6] = f2bf(b.z); pk.us[7] = f2bf(b.w);
    *(bf16x8*)(dst + (size_t)t * 8) = pk.v;
}

// GEMM screen: verbatim R19 (best) — 128^2 tile, BK=32, 32KB LDS, 4 blocks/CU,
// issue-first counted vmcnt(4) + raw s_barrier pairs, setprio around MFMA.
__global__ __launch_bounds__(256, 4) void gemm_screen(
    const unsigned short* __restrict__ Xbf, const unsigned short* __restrict__ Ebf2,
    const float* __restrict__ esqw, uint2* __restrict__ partials)
{
    __shared__ __align__(16) char pool[32768];

    const int tid = threadIdx.x;
    const int w = tid >> 6, lane = tid & 63;
    const int c = lane & 15, g = lane >> 4;
    const int bid = blockIdx.x;
    const int orig = (bid & 7) * 1024 + (bid >> 3);   // bijective: 8192 % 8 == 0
    const int rb = orig >> 5, cb = orig & 31;
    const int row0 = rb * 128, col0 = cb * 128;
    const int mw = w >> 1, nw = w & 1;

    const int hA = rb & 1, hB = cb & 1;
    const char* Xc = (const char*)Xbf  + (size_t)(rb >> 1) * 8 * 32768;
    const char* Ec = (const char*)Ebf2 + (size_t)(cb >> 1) * 8 * 32768;

    f32x4 acc[4][4];
    #pragma unroll
    for (int i = 0; i < 4; ++i)
        #pragma unroll
        for (int j = 0; j < 4; ++j) acc[i][j] = (f32x4){0.f, 0.f, 0.f, 0.f};

    #define STAGE(srcc_, h_, kt_, dstoff_) { \
        const char* sb_ = (srcc_) + (size_t)((kt_) >> 1) * 32768; \
        const int ks_ = (kt_) & 1; \
        _Pragma("unroll") for (int it_ = 0; it_ < 2; ++it_) { \
            const char* s_ = sb_ + (size_t)((((h_) * 8 + it_ * 4 + w) * 2 + ks_) * 64 + lane) * 16; \
            char* d_ = pool + (dstoff_) + (it_ * 4 + w) * 1024; \
            gll16(s_, d_); } }

    STAGE(Xc, hA, 0, 0); STAGE(Ec, hB, 0, 16384);
    int buf = 0;
    for (int kt = 0; kt < 16; ++kt) {
        if (kt < 15) {
            STAGE(Xc, hA, kt + 1, (buf ^ 1) * 8192);
            STAGE(Ec, hB, kt + 1, 16384 + (buf ^ 1) * 8192);
            asm volatile("s_waitcnt vmcnt(4)" ::: "memory");
        } else {
            asm volatile("s_waitcnt vmcnt(0)" ::: "memory");
        }
        __builtin_amdgcn_s_barrier();
        const char* Ap = pool + buf * 8192;
        const char* Bp = pool + 16384 + buf * 8192;
        bf16x8 af[4], bfr[4];
        #pragma unroll
        for (int i = 0; i < 4; ++i) {
            af[i]  = *(const bf16x8*)(Ap + (((mw * 4 + i) * 64) + lane) * 16);
            bfr[i] = *(const bf16x8*)(Bp + (((nw * 4 + i) * 64) + lane) * 16);
        }
        __builtin_amdgcn_s_setprio(1);
        #pragma unroll
        for (int mf = 0; mf < 4; ++mf)
            #pragma unroll
            for (int nf = 0; nf < 4; ++nf)
                acc[mf][nf] = __builtin_amdgcn_mfma_f32_16x16x32_bf16(af[mf], bfr[nf], acc[mf][nf], 0, 0, 0);
        __builtin_amdgcn_s_setprio(0);
        __builtin_amdgcn_s_barrier();
        buf ^= 1;
    }

    uint2* P = (uint2*)pool;
    #pragma unroll
    for (int mf = 0; mf < 4; ++mf) {
        #pragma unroll
        for (int r = 0; r < 4; ++r) {
            unsigned int q1 = 0xFFFFFFFFu, q2 = 0xFFFFFFFFu;
            int rowl = mw * 64 + mf * 16 + g * 4 + r;
            #pragma unroll
            for (int nf = 0; nf < 4; ++nf) {
                int col = col0 + nw * 64 + nf * 16 + c;
                float s = fmaf(-2.0f, acc[mf][nf][r], esqw[col]);
                unsigned int q = packscore(s, col);
                if (q < q1) { q2 = q1; q1 = q; } else if (q < q2) q2 = q;
            }
            P[(nw * 128 + rowl) * 16 + c] = make_uint2(q1, q2);
        }
    }
    __syncthreads();
    if (tid < 128) {
        int row = tid;
        #pragma unroll
        for (int n2 = 0; n2 < 2; ++n2) {
            unsigned int m1 = 0xFFFFFFFFu, m2 = 0xFFFFFFFFu;
            #pragma unroll 4
            for (int cc = 0; cc < 16; ++cc) {
                uint2 e = P[(n2 * 128 + row) * 16 + cc];
                if (e.x < m1) { m2 = m1; m1 = e.x; } else if (e.x < m2) m2 = e.x;
                if (e.y < m1) { m2 = m1; m1 = e.y; } else if (e.y < m2) m2 = e.y;
            }
            partials[(size_t)(cb * 2 + n2) * BB + row0 + row] = make_uint2(m1, m2);
        }
    }
    #undef STAGE
}

// FUSED finalize: per block 32 rows. Lanes 0-31: merge partials + numpy-fp32
// rescore (verbatim R5-R19) -> idx/hist/loss. Then all 256 threads stream the
// quantized gather + one-hot rows (coalesced float2).
__global__ __launch_bounds__(256) void finalize_kernel(
    const float* __restrict__ X, const float* __restrict__ E,
    const float* __restrict__ xsqw, const float* __restrict__ esqw,
    const uint2* __restrict__ partials, int* __restrict__ hist,
    double* __restrict__ loss_acc, float* __restrict__ out)
{
    __shared__ int sidx[32];
    __shared__ double lsr[32];
    const int tid = threadIdx.x;
    const int row0 = blockIdx.x * 32;

    if (tid < 32) {
        const int row = row0 + tid;
        unsigned int m = 0xFFFFFFFFu;
        for (int e = 0; e < 64; ++e) m = min(m, partials[(size_t)e * BB + row].x);
        float lim = unpackscore(m) + MARG;
        int cand[NCAND]; int nc = 0;
        for (int e = 0; e < 64; ++e) {
            uint2 p = partials[(size_t)e * BB + row];
            if (unpackscore(p.x) <= lim && nc < NCAND) cand[nc++] = (int)(p.x & 0xFFFu);
            if (unpackscore(p.y) <= lim && nc < NCAND) cand[nc++] = (int)(p.y & 0xFFFu);
        }
        const float* xr = X + (size_t)row * DD;
        float xs = xsqw[row];
        float bd = 3.0e38f; int bk = 0x7fffffff;
        for (int cidx = 0; cidx < nc; ++cidx) {
            int k = cand[cidx] & (KK - 1);
            const float* er = E + (size_t)k * DD;
            float q1 = 0.f, q2 = 0.f;
            for (int d = 0; d < 384; ++d)   q1 = fmaf(xr[d], er[d], q1);
            for (int d = 384; d < 512; ++d) q2 = fmaf(xr[d], er[d], q2);
            float dot = __fadd_rn(q1, q2);
            float t1  = __fadd_rn(xs, esqw[k]);
            float dnp = __fsub_rn(t1, __fmul_rn(2.0f, dot));
            if (dnp < bd || (dnp == bd && k < bk)) { bd = dnp; bk = k; }
        }
        const float* er = E + (size_t)bk * DD;
        double ls = 0.0;
        for (int d = 0; d < DD; ++d) {
            double df = (double)xr[d] - (double)er[d];
            ls = fma(df, df, ls);
        }
        sidx[tid] = bk;
        lsr[tid] = ls;
        out[IDX_OFF + row] = (float)bk;
        atomicAdd(&hist[bk], 1);
    }
    __syncthreads();
    if (tid == 0) {
        double s = 0.0;
        #pragma unroll 8
        for (int i = 0; i < 32; ++i) s += lsr[i];
        atomicAdd(loss_acc, s);
    }
    // quantized gather: 32 rows x 256 float2 (coalesced)
    #pragma unroll 4
    for (int r = 0; r < 32; ++r) {
        int idx = sidx[r];
        ((float2*)out)[(size_t)(row0 + r) * 256 + tid] =
            ((const float2*)E)[(size_t)idx * 256 + tid];
    }
    // one-hot rows: 32 rows x 2048 float2 (8 iters of 256 threads)
    for (int r = 0; r < 32; ++r) {
        int idx = sidx[r];
        float2* erow = (float2*)(out + ENC_OFF) + (size_t)(row0 + r) * (KK / 2);
        int half = idx >> 1;
        float2 one;
        if (idx & 1) { one.x = 0.f; one.y = 1.f; } else { one.x = 1.f; one.y = 0.f; }
        float2 z; z.x = 0.f; z.y = 0.f;
        #pragma unroll
        for (int j = 0; j < 8; ++j) {
            int cc = tid + j * 256;
            erow[cc] = (cc == half) ? one : z;
        }
    }
}

__global__ __launch_bounds__(256) void fin_kernel(const int* __restrict__ hist,
                                                  const double* __restrict__ loss_acc,
                                                  float* __restrict__ out) {
    __shared__ double red[256];
    int tid = threadIdx.x;
    double s = 0.0;
    for (int k = tid; k < KK; k += 256) {
        double p = (double)hist[k] * (1.0 / 32768.0);
        s += p * log(p + 1e-10);
    }
    red[tid] = s;
    __syncthreads();
    for (int t = 128; t > 0; t >>= 1) {
        if (tid < t) red[tid] += red[tid + t];
        __syncthreads();
    }
    if (tid == 0) {
        double perp = exp(-red[0]);
        double L = loss_acc[0] * (1.0 / ((double)BB * (double)DD));
        out[LOSS_OFF] = (float)(1.25 * L);
        out[PERP_OFF] = (float)perp;
    }
}

extern "C" void kernel_launch(void* const* d_in, const int* in_sizes, int n_in,
                              void* d_out, int out_size, void* d_ws, size_t ws_size,
                              hipStream_t stream) {
    const float* X; const float* E;
    if (in_sizes[0] == BB * DD) { X = (const float*)d_in[0]; E = (const float*)d_in[1]; }
    else                        { X = (const float*)d_in[1]; E = (const float*)d_in[0]; }
    float* out = (float*)d_out;

    float* xsq = (float*)((char*)d_ws + WSB_XSQ);
    float* esq = (float*)((char*)d_ws + WSB_ESQ);
    int* hist   = (int*)((char*)d_ws + WSB_HIST);
    double* loss_acc = (double*)((char*)d_ws + WSB_LOSS);
    unsigned short* Ebf2 = (unsigned short*)((char*)d_ws + WSB_EBF2);
    unsigned short* Xbf  = (unsigned short*)((char*)d_ws + WSB_XBF);
    uint2* partials = (uint2*)((char*)d_ws + WSB_PART);

    hipLaunchKernelGGL(npsum_pack_kernel, dim3((BB + KK) / 4), dim3(256), 0, stream,
                       X, E, xsq, esq, Xbf);
    hipLaunchKernelGGL(packE_kernel, dim3(1024), dim3(256), 0, stream,
                       E, Ebf2, hist, loss_acc);
    hipLaunchKernelGGL(gemm_screen, dim3(8192), dim3(256), 0, stream,
                       Xbf, Ebf2, esq, partials);
    hipLaunchKernelGGL(finalize_kernel, dim3(BB / 32), dim3(256), 0, stream,
                       X, E, xsq, esq, partials, hist, loss_acc, out);
    hipLaunchKernelGGL(fin_kernel, dim3(1), dim3(256), 0, stream, hist, loss_acc, out);
}

// Round 21
// 444.088 us; speedup vs baseline: 1.3975x; 1.0006x over previous
//
#include <hip/hip_runtime.h>
#include <hip/hip_bf16.h>

// VectorQuantizer B=32768, K=4096, D=512, fp32 in/out.
// Out concat (f32): quantized_st[B*512] | indices[B] | loss | perplexity | encodings[B*4096].
// R21: R20 (best, 444us) minus the packE launch: the E-pack uses the SAME unit
// formula as the X-pack, so npsum_pack emits Ebf2 for its E rows directly
// (one less launch, one less 8MB E read). hist/loss init folded into npsum's
// first blocks. Screen + finalize byte-identical to R20.

typedef __attribute__((ext_vector_type(8))) short bf16x8;
typedef __attribute__((ext_vector_type(4))) float f32x4;

#define BB 32768
#define KK 4096
#define DD 512

#define IDX_OFF  (BB*DD)
#define LOSS_OFF (IDX_OFF + BB)
#define PERP_OFF (LOSS_OFF + 1)
#define ENC_OFF  (PERP_OFF + 1)

// ws byte offsets
#define WSB_XSQ  0
#define WSB_ESQ  131072
#define WSB_HIST 278528
#define WSB_LOSS 294912
#define WSB_EBF2 294928          // 4 MB: E bf16, packed per (cb2,kt64) 32KB chunk
#define WSB_XBF  4489232         // 32 MB: X bf16, packed per (rb2,kt64) 32KB chunk
#define WSB_PART 38043664        // 16 MB: uint2 partials [64][32768]

#define MARG 2.5e-4f
#define NCAND 16

static __device__ __forceinline__ unsigned short f2bf(float f) {
    __hip_bfloat16 h = __float2bfloat16(f);
    return *reinterpret_cast<unsigned short*>(&h);
}

static __device__ __forceinline__ unsigned int packscore(float s, int col) {
    unsigned int u = __float_as_uint(s);
    u ^= (u & 0x80000000u) ? 0xFFFFFFFFu : 0x80000000u;
    return (u & 0xFFFFF000u) | (unsigned int)col;
}
static __device__ __forceinline__ float unpackscore(unsigned int p) {
    unsigned int u = p & 0xFFFFF000u;
    u = (u & 0x80000000u) ? (u ^ 0x80000000u) : ~u;
    return __uint_as_float(u);
}

static __device__ __forceinline__ void gll16(const void* g, void* l) {
    __builtin_amdgcn_global_load_lds(
        (const __attribute__((address_space(1))) unsigned int*)g,
        (__attribute__((address_space(3))) unsigned int*)l, 16, 0, 0);
}

// numpy-emulated row sum-of-squares (pairwise-128 + AVX512 lane fold; tree math
// bit-identical R5-R20) fused with bf16 fragment-packing for BOTH X and E
// (identical unit formula), plus hist/loss init in the first 17 blocks.
__global__ __launch_bounds__(256) void npsum_pack_kernel(const float* __restrict__ X,
                                                         const float* __restrict__ E,
                                                         float* __restrict__ xsq,
                                                         float* __restrict__ esq,
                                                         unsigned short* __restrict__ Xbf,
                                                         unsigned short* __restrict__ Ebf2,
                                                         int* __restrict__ hist,
                                                         double* __restrict__ loss_acc) {
    __shared__ float sq[4][512];
    __shared__ float ub[4][64];
    __shared__ float bb[4][4];
    {   // fused init (hist consumed only by finalize, later in stream)
        int gi = blockIdx.x * 256 + threadIdx.x;
        if (gi < KK) hist[gi] = 0;
        if (gi == KK) *loss_acc = 0.0;
    }
    int w = threadIdx.x >> 6, lane = threadIdx.x & 63;
    int row = blockIdx.x * 4 + w;
    const float* src; float* dst;
    bool isx = (row < BB);
    int lr = isx ? row : row - BB;     // local row within X or E
    if (isx) { src = X + (size_t)lr * DD; dst = xsq + lr; }
    else     { src = E + (size_t)lr * DD; dst = esq + lr; }
    const float4* s4 = (const float4*)(src + lane * 8);
    float4 a = s4[0], b = s4[1];
    sq[w][lane * 8 + 0] = __fmul_rn(a.x, a.x);
    sq[w][lane * 8 + 1] = __fmul_rn(a.y, a.y);
    sq[w][lane * 8 + 2] = __fmul_rn(a.z, a.z);
    sq[w][lane * 8 + 3] = __fmul_rn(a.w, a.w);
    sq[w][lane * 8 + 4] = __fmul_rn(b.x, b.x);
    sq[w][lane * 8 + 5] = __fmul_rn(b.y, b.y);
    sq[w][lane * 8 + 6] = __fmul_rn(b.z, b.z);
    sq[w][lane * 8 + 7] = __fmul_rn(b.w, b.w);
    {   // fragment-pack unit for [lr][lane*8 ..+7] (same formula both operands)
        int kt64 = lane >> 3, ks = (lane >> 2) & 1, oct = lane & 3;
        int rf = (lr >> 4) & 15;
        size_t unit = ((size_t)((lr >> 8) * 8 + kt64)) * 2048
                    + (size_t)((rf * 2 + ks) * 64 + oct * 16 + (lr & 15));
        union { bf16x8 v; unsigned short us[8]; } pk;
        pk.us[0] = f2bf(a.x); pk.us[1] = f2bf(a.y); pk.us[2] = f2bf(a.z); pk.us[3] = f2bf(a.w);
        pk.us[4] = f2bf(b.x); pk.us[5] = f2bf(b.y); pk.us[6] = f2bf(b.z); pk.us[7] = f2bf(b.w);
        unsigned short* pb = isx ? Xbf : Ebf2;
        *(bf16x8*)(pb + unit * 8) = pk.v;
    }
    __syncthreads();
    {
        int b2 = lane >> 4, l = lane & 15;
        const float* s = &sq[w][b2 * 128];
        float t = __fadd_rn(
            __fadd_rn(__fadd_rn(s[l], s[16 + l]), __fadd_rn(s[32 + l], s[48 + l])),
            __fadd_rn(__fadd_rn(s[64 + l], s[80 + l]), __fadd_rn(s[96 + l], s[112 + l])));
        ub[w][lane] = t;
    }
    __syncthreads();
    if (lane < 4) {
        const float* u = &ub[w][lane * 16];
        float T3[8], T6[4];
        #pragma unroll
        for (int i = 0; i < 8; ++i) T3[i] = __fadd_rn(u[i], u[i + 8]);
        #pragma unroll
        for (int i = 0; i < 4; ++i) T6[i] = __fadd_rn(T3[i], T3[i + 4]);
        bb[w][lane] = __fadd_rn(__fadd_rn(T6[0], T6[2]), __fadd_rn(T6[1], T6[3]));
    }
    __syncthreads();
    if (lane == 0)
        *dst = __fadd_rn(__fadd_rn(bb[w][0], bb[w][1]), __fadd_rn(bb[w][2], bb[w][3]));
}

// GEMM screen: verbatim R19/R20 (best) — 128^2 tile, BK=32, 32KB LDS, 4 blocks/CU,
// issue-first counted vmcnt(4) + raw s_barrier pairs, setprio around MFMA.
__global__ __launch_bounds__(256, 4) void gemm_screen(
    const unsigned short* __restrict__ Xbf, const unsigned short* __restrict__ Ebf2,
    const float* __restrict__ esqw, uint2* __restrict__ partials)
{
    __shared__ __align__(16) char pool[32768];

    const int tid = threadIdx.x;
    const int w = tid >> 6, lane = tid & 63;
    const int c = lane & 15, g = lane >> 4;
    const int bid = blockIdx.x;
    const int orig = (bid & 7) * 1024 + (bid >> 3);   // bijective: 8192 % 8 == 0
    const int rb = orig >> 5, cb = orig & 31;
    const int row0 = rb * 128, col0 = cb * 128;
    const int mw = w >> 1, nw = w & 1;

    const int hA = rb & 1, hB = cb & 1;
    const char* Xc = (const char*)Xbf  + (size_t)(rb >> 1) * 8 * 32768;
    const char* Ec = (const char*)Ebf2 + (size_t)(cb >> 1) * 8 * 32768;

    f32x4 acc[4][4];
    #pragma unroll
    for (int i = 0; i < 4; ++i)
        #pragma unroll
        for (int j = 0; j < 4; ++j) acc[i][j] = (f32x4){0.f, 0.f, 0.f, 0.f};

    #define STAGE(srcc_, h_, kt_, dstoff_) { \
        const char* sb_ = (srcc_) + (size_t)((kt_) >> 1) * 32768; \
        const int ks_ = (kt_) & 1; \
        _Pragma("unroll") for (int it_ = 0; it_ < 2; ++it_) { \
            const char* s_ = sb_ + (size_t)((((h_) * 8 + it_ * 4 + w) * 2 + ks_) * 64 + lane) * 16; \
            char* d_ = pool + (dstoff_) + (it_ * 4 + w) * 1024; \
            gll16(s_, d_); } }

    STAGE(Xc, hA, 0, 0); STAGE(Ec, hB, 0, 16384);
    int buf = 0;
    for (int kt = 0; kt < 16; ++kt) {
        if (kt < 15) {
            STAGE(Xc, hA, kt + 1, (buf ^ 1) * 8192);
            STAGE(Ec, hB, kt + 1, 16384 + (buf ^ 1) * 8192);
            asm volatile("s_waitcnt vmcnt(4)" ::: "memory");
        } else {
            asm volatile("s_waitcnt vmcnt(0)" ::: "memory");
        }
        __builtin_amdgcn_s_barrier();
        const char* Ap = pool + buf * 8192;
        const char* Bp = pool + 16384 + buf * 8192;
        bf16x8 af[4], bfr[4];
        #pragma unroll
        for (int i = 0; i < 4; ++i) {
            af[i]  = *(const bf16x8*)(Ap + (((mw * 4 + i) * 64) + lane) * 16);
            bfr[i] = *(const bf16x8*)(Bp + (((nw * 4 + i) * 64) + lane) * 16);
        }
        __builtin_amdgcn_s_setprio(1);
        #pragma unroll
        for (int mf = 0; mf < 4; ++mf)
            #pragma unroll
            for (int nf = 0; nf < 4; ++nf)
                acc[mf][nf] = __builtin_amdgcn_mfma_f32_16x16x32_bf16(af[mf], bfr[nf], acc[mf][nf], 0, 0, 0);
        __builtin_amdgcn_s_setprio(0);
        __builtin_amdgcn_s_barrier();
        buf ^= 1;
    }

    uint2* P = (uint2*)pool;
    #pragma unroll
    for (int mf = 0; mf < 4; ++mf) {
        #pragma unroll
        for (int r = 0; r < 4; ++r) {
            unsigned int q1 = 0xFFFFFFFFu, q2 = 0xFFFFFFFFu;
            int rowl = mw * 64 + mf * 16 + g * 4 + r;
            #pragma unroll
            for (int nf = 0; nf < 4; ++nf) {
                int col = col0 + nw * 64 + nf * 16 + c;
                float s = fmaf(-2.0f, acc[mf][nf][r], esqw[col]);
                unsigned int q = packscore(s, col);
                if (q < q1) { q2 = q1; q1 = q; } else if (q < q2) q2 = q;
            }
            P[(nw * 128 + rowl) * 16 + c] = make_uint2(q1, q2);
        }
    }
    __syncthreads();
    if (tid < 128) {
        int row = tid;
        #pragma unroll
        for (int n2 = 0; n2 < 2; ++n2) {
            unsigned int m1 = 0xFFFFFFFFu, m2 = 0xFFFFFFFFu;
            #pragma unroll 4
            for (int cc = 0; cc < 16; ++cc) {
                uint2 e = P[(n2 * 128 + row) * 16 + cc];
                if (e.x < m1) { m2 = m1; m1 = e.x; } else if (e.x < m2) m2 = e.x;
                if (e.y < m1) { m2 = m1; m1 = e.y; } else if (e.y < m2) m2 = e.y;
            }
            partials[(size_t)(cb * 2 + n2) * BB + row0 + row] = make_uint2(m1, m2);
        }
    }
    #undef STAGE
}

// FUSED finalize (verbatim R20): 32 rows/block; lanes 0-31 rescore via numpy-fp32
// emulation; block-wide coalesced quantized gather + one-hot writes.
__global__ __launch_bounds__(256) void finalize_kernel(
    const float* __restrict__ X, const float* __restrict__ E,
    const float* __restrict__ xsqw, const float* __restrict__ esqw,
    const uint2* __restrict__ partials, int* __restrict__ hist,
    double* __restrict__ loss_acc, float* __restrict__ out)
{
    __shared__ int sidx[32];
    __shared__ double lsr[32];
    const int tid = threadIdx.x;
    const int row0 = blockIdx.x * 32;

    if (tid < 32) {
        const int row = row0 + tid;
        unsigned int m = 0xFFFFFFFFu;
        for (int e = 0; e < 64; ++e) m = min(m, partials[(size_t)e * BB + row].x);
        float lim = unpackscore(m) + MARG;
        int cand[NCAND]; int nc = 0;
        for (int e = 0; e < 64; ++e) {
            uint2 p = partials[(size_t)e * BB + row];
            if (unpackscore(p.x) <= lim && nc < NCAND) cand[nc++] = (int)(p.x & 0xFFFu);
            if (unpackscore(p.y) <= lim && nc < NCAND) cand[nc++] = (int)(p.y & 0xFFFu);
        }
        const float* xr = X + (size_t)row * DD;
        float xs = xsqw[row];
        float bd = 3.0e38f; int bk = 0x7fffffff;
        for (int cidx = 0; cidx < nc; ++cidx) {
            int k = cand[cidx] & (KK - 1);
            const float* er = E + (size_t)k * DD;
            float q1 = 0.f, q2 = 0.f;
            for (int d = 0; d < 384; ++d)   q1 = fmaf(xr[d], er[d], q1);
            for (int d = 384; d < 512; ++d) q2 = fmaf(xr[d], er[d], q2);
            float dot = __fadd_rn(q1, q2);
            float t1  = __fadd_rn(xs, esqw[k]);
            float dnp = __fsub_rn(t1, __fmul_rn(2.0f, dot));
            if (dnp < bd || (dnp == bd && k < bk)) { bd = dnp; bk = k; }
        }
        const float* er = E + (size_t)bk * DD;
        double ls = 0.0;
        for (int d = 0; d < DD; ++d) {
            double df = (double)xr[d] - (double)er[d];
            ls = fma(df, df, ls);
        }
        sidx[tid] = bk;
        lsr[tid] = ls;
        out[IDX_OFF + row] = (float)bk;
        atomicAdd(&hist[bk], 1);
    }
    __syncthreads();
    if (tid == 0) {
        double s = 0.0;
        #pragma unroll 8
        for (int i = 0; i < 32; ++i) s += lsr[i];
        atomicAdd(loss_acc, s);
    }
    #pragma unroll 4
    for (int r = 0; r < 32; ++r) {
        int idx = sidx[r];
        ((float2*)out)[(size_t)(row0 + r) * 256 + tid] =
            ((const float2*)E)[(size_t)idx * 256 + tid];
    }
    for (int r = 0; r < 32; ++r) {
        int idx = sidx[r];
        float2* erow = (float2*)(out + ENC_OFF) + (size_t)(row0 + r) * (KK / 2);
        int half = idx >> 1;
        float2 one;
        if (idx & 1) { one.x = 0.f; one.y = 1.f; } else { one.x = 1.f; one.y = 0.f; }
        float2 z; z.x = 0.f; z.y = 0.f;
        #pragma unroll
        for (int j = 0; j < 8; ++j) {
            int cc = tid + j * 256;
            erow[cc] = (cc == half) ? one : z;
        }
    }
}

__global__ __launch_bounds__(256) void fin_kernel(const int* __restrict__ hist,
                                                  const double* __restrict__ loss_acc,
                                                  float* __restrict__ out) {
    __shared__ double red[256];
    int tid = threadIdx.x;
    double s = 0.0;
    for (int k = tid; k < KK; k += 256) {
        double p = (double)hist[k] * (1.0 / 32768.0);
        s += p * log(p + 1e-10);
    }
    red[tid] = s;
    __syncthreads();
    for (int t = 128; t > 0; t >>= 1) {
        if (tid < t) red[tid] += red[tid + t];
        __syncthreads();
    }
    if (tid == 0) {
        double perp = exp(-red[0]);
        double L = loss_acc[0] * (1.0 / ((double)BB * (double)DD));
        out[LOSS_OFF] = (float)(1.25 * L);
        out[PERP_OFF] = (float)perp;
    }
}

extern "C" void kernel_launch(void* const* d_in, const int* in_sizes, int n_in,
                              void* d_out, int out_size, void* d_ws, size_t ws_size,
                              hipStream_t stream) {
    const float* X; const float* E;
    if (in_sizes[0] == BB * DD) { X = (const float*)d_in[0]; E = (const float*)d_in[1]; }
    else                        { X = (const float*)d_in[1]; E = (const float*)d_in[0]; }
    float* out = (float*)d_out;

    float* xsq = (float*)((char*)d_ws + WSB_XSQ);
    float* esq = (float*)((char*)d_ws + WSB_ESQ);
    int* hist   = (int*)((char*)d_ws + WSB_HIST);
    double* loss_acc = (double*)((char*)d_ws + WSB_LOSS);
    unsigned short* Ebf2 = (unsigned short*)((char*)d_ws + WSB_EBF2);
    unsigned short* Xbf  = (unsigned short*)((char*)d_ws + WSB_XBF);
    uint2* partials = (uint2*)((char*)d_ws + WSB_PART);

    hipLaunchKernelGGL(npsum_pack_kernel, dim3((BB + KK) / 4), dim3(256), 0, stream,
                       X, E, xsq, esq, Xbf, Ebf2, hist, loss_acc);
    hipLaunchKernelGGL(gemm_screen, dim3(8192), dim3(256), 0, stream,
                       Xbf, Ebf2, esq, partials);
    hipLaunchKernelGGL(finalize_kernel, dim3(BB / 32), dim3(256), 0, stream,
                       X, E, xsq, esq, partials, hist, loss_acc, out);
    hipLaunchKernelGGL(fin_kernel, dim3(1), dim3(256), 0, stream, hist, loss_acc, out);
}